// Round 5
// baseline (111.510 us; speedup 1.0000x reference)
//
#include <hip/hip_runtime.h>
#include <cmath>

// pa_lif: T=8, tau=0.25, thresh=0.5. Per-column recurrence (absmax 0.0, R2/R4):
//   w[i]   = 0.25*x[i] + 0.75*w[i-1]                      (W_CONST @ x as IIR)
//   p1[i]  = sigmoid(0.5 - 0.5*(0.25*x[i] + w[i]))
//   pre[i] = 0.25*(x[i] + S[i]) - 0.5 ;  out[i] = pre[i] > 0
//   S[i+1] = 0.25*p1[i]*(S[i] + x[i]) ;  S[0] = 0
// Last step (i=7): p1/S-update are dead (feed only unused S[8]) -> skipped,
// deleting 4 of 32 expf per thread (and 1/8 of the rare fp64-exp work).
//
// Heaviside output: one sign flip = absmax 1.0, so boundary cases (min |pre| <
// 5e-5, ~0.4% of threads) are recomputed in fp64 (verified exact vs np ref).
// Determinism rule (round-1 lesson): every output address is written by
// EXACTLY ONE store site per launch — fast-store and refine-store are
// exclusive branches, no overwrites.

#define TT 8

// native vector type: __builtin_nontemporal_store requires a real vector,
// not HIP's float4 class
typedef float vfloat4 __attribute__((ext_vector_type(4)));

// one fp32 recurrence step for a single column (tracks min |pre| in `mn`)
#define STEP32(xik, w, S, o)                                  \
    {                                                         \
        float xk_ = (xik);                                    \
        w = fmaf(0.75f, w, 0.25f * xk_);                      \
        float arg_ = 0.5f - 0.5f * fmaf(0.25f, xk_, w);       \
        float p1_ = 1.0f / (1.0f + expf(-arg_));              \
        float pre_ = fmaf(0.25f, (xk_ + S), -0.5f);           \
        o = (pre_ > 0.0f) ? 1.0f : 0.0f;                      \
        float a_ = fabsf(pre_);                               \
        mn = (a_ < mn) ? a_ : mn;                             \
        S = 0.25f * p1_ * (S + xk_);                          \
    }

// final fp32 step: only pre/sign/mn needed (no p1, no S update, no w update)
#define LAST32(xik, S, o)                                     \
    {                                                         \
        float xk_ = (xik);                                    \
        float pre_ = fmaf(0.25f, (xk_ + S), -0.5f);           \
        o = (pre_ > 0.0f) ? 1.0f : 0.0f;                      \
        float a_ = fabsf(pre_);                               \
        mn = (a_ < mn) ? a_ : mn;                             \
    }

// one fp64 recurrence step (rare path; matches R2's refine bit-for-bit)
#define STEP64(xif, wd, Sd, o)                                \
    {                                                         \
        double xd_ = (double)(xif);                           \
        wd = 0.25 * xd_ + 0.75 * wd;                          \
        double arg_ = 0.5 - 0.5 * (0.25 * xd_ + wd);          \
        double p1_ = 1.0 / (1.0 + exp(-arg_));                \
        double pre_ = 0.25 * (xd_ + Sd) - 0.5;                \
        o = (pre_ > 0.0) ? 1.0f : 0.0f;                       \
        Sd = 0.25 * p1_ * (Sd + xd_);                         \
    }

// final fp64 step: sign only
#define LAST64(xif, Sd, o)                                    \
    {                                                         \
        double xd_ = (double)(xif);                           \
        double pre_ = 0.25 * (xd_ + Sd) - 0.5;                \
        o = (pre_ > 0.0) ? 1.0f : 0.0f;                       \
    }

__global__ __launch_bounds__(256)
void pa_lif_kernel(const float* __restrict__ x, float* __restrict__ out, int dim4) {
    int tid = blockIdx.x * blockDim.x + threadIdx.x;
    if (tid >= dim4) return;

    const float4* __restrict__ xv = (const float4*)x;
    float4* __restrict__ ov = (float4*)out;
    vfloat4* __restrict__ onv = (vfloat4*)out;

    float4 ot[TT];
    float w0 = 0.f, w1 = 0.f, w2 = 0.f, w3 = 0.f;
    float S0 = 0.f, S1 = 0.f, S2 = 0.f, S3 = 0.f;
    float mn = 1e30f;

    // consume each row as it arrives; only ot[] stays live
#pragma unroll
    for (int i = 0; i < TT - 1; ++i) {
        float4 xi = xv[(size_t)i * dim4 + tid];
        STEP32(xi.x, w0, S0, ot[i].x);
        STEP32(xi.y, w1, S1, ot[i].y);
        STEP32(xi.z, w2, S2, ot[i].z);
        STEP32(xi.w, w3, S3, ot[i].w);
    }
    {
        float4 xi = xv[(size_t)(TT - 1) * dim4 + tid];
        LAST32(xi.x, S0, ot[TT - 1].x);
        LAST32(xi.y, S1, ot[TT - 1].y);
        LAST32(xi.z, S2, ot[TT - 1].z);
        LAST32(xi.w, S3, ot[TT - 1].w);
    }

    if (__builtin_expect(mn >= 5e-5f, 1)) {
        // write-once stream: bypass L2 with nontemporal 16B stores
#pragma unroll
        for (int i = 0; i < TT; ++i) {
            vfloat4 o = {ot[i].x, ot[i].y, ot[i].z, ot[i].w};
            __builtin_nontemporal_store(o, &onv[(size_t)i * dim4 + tid]);
        }
    } else {
        // rare fp64 recompute; reload x (L2/L3-warm), rolled loop keeps the
        // double-exp code small and out of the hot path's register budget
        double wd0 = 0, wd1 = 0, wd2 = 0, wd3 = 0;
        double Sd0 = 0, Sd1 = 0, Sd2 = 0, Sd3 = 0;
#pragma unroll 1
        for (int i = 0; i < TT - 1; ++i) {
            float4 xi = xv[(size_t)i * dim4 + tid];
            float4 o;
            STEP64(xi.x, wd0, Sd0, o.x);
            STEP64(xi.y, wd1, Sd1, o.y);
            STEP64(xi.z, wd2, Sd2, o.z);
            STEP64(xi.w, wd3, Sd3, o.w);
            ov[(size_t)i * dim4 + tid] = o;
        }
        {
            float4 xi = xv[(size_t)(TT - 1) * dim4 + tid];
            float4 o;
            LAST64(xi.x, Sd0, o.x);
            LAST64(xi.y, Sd1, o.y);
            LAST64(xi.z, Sd2, o.z);
            LAST64(xi.w, Sd3, o.w);
            ov[(size_t)(TT - 1) * dim4 + tid] = o;
        }
    }
}

extern "C" void kernel_launch(void* const* d_in, const int* in_sizes, int n_in,
                              void* d_out, int out_size, void* d_ws, size_t ws_size,
                              hipStream_t stream) {
    (void)n_in; (void)out_size; (void)d_ws; (void)ws_size;
    const float* x = (const float*)d_in[0];
    float* out = (float*)d_out;
    int total = in_sizes[0];        // T * dim = 16,777,216
    int dim = total / TT;           // 2,097,152 columns
    int dim4 = dim / 4;             // 524,288 threads (float4 per thread)
    int block = 256;
    int grid = (dim4 + block - 1) / block;
    pa_lif_kernel<<<grid, block, 0, stream>>>(x, out, dim4);
}